// Round 14
// baseline (77.653 us; speedup 1.0000x reference)
//
#include <hip/hip_runtime.h>

// Smith-Waterman soft-DP, B=512, x: (512,151,151) f32, scalar output.
// One DP wave per batch (512 blocks x 256 threads; waves 1-3 only help the
// LDS staging then exit). Linear-domain DP (H = exp(h) * 2^-E).
// Phase A: coalesced read of x[b], exp2 -> fp8(e4m3) scattered into a
// diag-major LDS layout [t][4*lane+k] (308x256B = 77KB).
// Phase B: per step ONE ds_read_b32 (imm-offset addressing, no clamps),
// 3 v_cvt_f32_fp8 commits, 4-step register FIFO, 2-3 bound-ctrl DPPs,
// per-k S accumulators, renorm every 8 steps with early decision.

#define CGO 6.737946999085467e-03f   // e^-5
#define CGE 3.678794411714423e-01f   // e^-1
#define L2E 1.4426950408889634f
#define LN2 0.6931471805599453f
#define RTHR 0x1p36f
#define RSC  0x1p-80f
#define EADD 80.0f

#if __has_builtin(__builtin_amdgcn_exp2f)
#define EXP2(x) __builtin_amdgcn_exp2f(x)
#else
static __device__ __forceinline__ float EXP2_(float x){float r;asm("v_exp_f32 %0, %1":"=v"(r):"v"(x));return r;}
#define EXP2(x) EXP2_(x)
#endif

#if __has_builtin(__builtin_amdgcn_logf)
#define LOG2(x) __builtin_amdgcn_logf(x)
#else
static __device__ __forceinline__ float LOG2_(float x){float r;asm("v_log_f32 %0, %1":"=v"(r):"v"(x));return r;}
#define LOG2(x) LOG2_(x)
#endif

// ---- fp8 e4m3fn encode/decode (sign always 0 for exp-domain values) ----
#if __has_builtin(__builtin_amdgcn_cvt_f32_fp8)
#define CVT8(w, s) __builtin_amdgcn_cvt_f32_fp8((int)(w), (s))
#else
static __device__ __forceinline__ float CVT8_(unsigned w, int s){
    const unsigned b = (w >> (8 * s)) & 0xFFu;
    const unsigned e = (b >> 3) & 0xFu, m = b & 7u;
    return (e == 0) ? ((float)m * 0x1p-9f)
                    : __uint_as_float(((e + 120u) << 23) | (m << 20));
}
#define CVT8(w, s) CVT8_((w), (s))
#endif

#if __has_builtin(__builtin_amdgcn_cvt_pk_fp8_f32)
#define PK8(v) ((unsigned)__builtin_amdgcn_cvt_pk_fp8_f32((v), (v), 0, false) & 0xFFu)
#else
static __device__ __forceinline__ unsigned PK8_(float v){
    v = fminf(v, 448.0f);
    if (!(v >= 0x1p-10f)) return 0u;
    const unsigned u = __float_as_uint(v);
    int e = (int)((u >> 23) & 0xFFu) - 127;
    if (e < -6) {
        const int M = (int)(v * 512.0f + 0.5f);
        return (M > 7) ? 0x08u : (unsigned)M;
    }
    unsigned keep = (u >> 20) & 7u;
    const unsigned rest = u & 0xFFFFFu;
    keep += (rest > 0x80000u) || (rest == 0x80000u && (keep & 1u));
    if (keep == 8u) { keep = 0u; e += 1; }
    if (e > 8) return 0x7Eu;
    return (unsigned)(((e + 7) << 3) | keep);
}
#define PK8(v) PK8_(v)
#endif

#define DPP_UP 0x138   // wave_shr:1  (lane i <- i-1; lane 0 -> bound 0)
#define DPP_DN 0x130   // wave_shl:1  (lane i <- i+1; lane 63 -> bound 0)

template<int CTRL>
static __device__ __forceinline__ float dppz(float v){   // invalid lanes -> 0
    return __int_as_float(__builtin_amdgcn_update_dpp(
        0, __float_as_int(v), CTRL, 0xF, 0xF, true));
}

// ---- one anti-diagonal step (SO = d&1, compile-time) ----
// Slot j = 3*lane + k. Entry: Vs[k] = exp(cell) diag d (f32), Vx[k] = diag
// d+2, Rc = fp8x4 dword of diag d+4 (loaded at step d-4).
// Order: compute -> commit Vs[k] <- cvt_fp8(Rc,k) -> load Rc <- row(d+8).
template<int SO>
static __device__ __forceinline__
void stepQ(const int d, const int j3, const int lane, const unsigned* rowp,
           float (&H1)[3][3], float (&H2)[3][3],
           float (&Vs)[3], float (&Vx)[3], unsigned& Rc,
           const float oneE, float (&S)[3], const bool isL50)
{
    const int half = (149 + d) >> 1;
    const int cvlo = half - (d < 149 ? d : 149);
    const int cvhi = half - (d > 149 ? d - 149 : 0);

    // neighbor components under packed mapping (h1 = H1)
    float R0[3], R1[3], D0[3], D1[3], D2[3];
    if (SO) {   // odd: right <- h1[j-1]; down <- own h1
        R0[0] = dppz<DPP_UP>(H1[2][0]);     // j-1 = 3(lane-1)+2
        R1[0] = dppz<DPP_UP>(H1[2][1]);
        R0[1] = H1[0][0]; R1[1] = H1[0][1]; // j-1 = own k=0
        R0[2] = H1[1][0]; R1[2] = H1[1][1]; // j-1 = own k=1
        #pragma unroll
        for (int k = 0; k < 3; ++k) { D0[k]=H1[k][0]; D1[k]=H1[k][1]; D2[k]=H1[k][2]; }
    } else {    // even: right <- own h1; down <- h1[j+1]
        #pragma unroll
        for (int k = 0; k < 3; ++k) { R0[k]=H1[k][0]; R1[k]=H1[k][1]; }
        D0[0] = H1[1][0]; D1[0] = H1[1][1]; D2[0] = H1[1][2];  // j+1 = own k=1
        D0[1] = H1[2][0]; D1[1] = H1[2][1]; D2[1] = H1[2][2];  // j+1 = own k=2
        D0[2] = dppz<DPP_DN>(H1[0][0]);     // j+1 = 3(lane+1)+0
        D1[2] = dppz<DPP_DN>(H1[0][1]);
        D2[2] = dppz<DPP_DN>(H1[0][2]);
    }

    #pragma unroll
    for (int k = 0; k < 3; ++k) {
        const int j = j3 + k;
        const bool cv = (j >= cvlo) && (j <= cvhi);
        const float sxl = cv ? Vs[k] : 0.0f;
        const float x2l = cv ? Vx[k] : 0.0f;

        float h0 = sxl * ((H2[k][0] + H2[k][1]) + (H2[k][2] + oneE));
        float h1 = fmaf(CGO, R0[k], CGE * R1[k]);
        float h2 = fmaf(CGO, D0[k] + D1[k], CGE * D2[k]);
        if (k == 0) {   // slot 150 (lane 50, k=0) is the only pad slot a real
            h1 = isL50 ? 0.0f : h1;   // cell ever reads; force exact sentinel.
            h2 = isL50 ? 0.0f : h2;   // (h0 already 0 via cv.) Slots 151+ stay 0.
        }
        S[k] = fmaf(x2l, (h0 + h1) + h2, S[k]);
        H2[k][0] = h0; H2[k][1] = h1; H2[k][2] = h2;
    }

    // commit: Vs <- cvt(Rc)  [Rc holds diag d+4, loaded 4 steps ago]
    Vs[0] = CVT8(Rc, 0); Vs[1] = CVT8(Rc, 1); Vs[2] = CVT8(Rc, 2);
    // load diag d+8 DIRECTLY into Rc (one dword; consumed at step d+4)
    Rc = rowp[(d + 8) * 64 + lane];
}

__global__ __launch_bounds__(256)
void sw_fp8(const float* __restrict__ x, float* __restrict__ part,
            float* __restrict__ out_atomic, int use_atomic) {
    const int b = blockIdx.x;
    const float* xb = x + (size_t)b * 22801;
    const int tid = threadIdx.x;

    __shared__ unsigned ldsW[308 * 64];   // diag-major fp8: row t, byte 4*lane+k

    // ---- phase A0: zero-init (all 4 waves) ----
    {
        int4* l4 = (int4*)ldsW;
        for (int i = tid; i < (308 * 256) / 16; i += 256)
            l4[i] = int4{0, 0, 0, 0};
    }
    __syncthreads();

    // ---- phase A1: coalesced load + exp -> fp8 scatter (all 4 waves) ----
    for (int i = 0; i < 90; ++i) {
        const int idx = i * 256 + tid;
        if (idx < 22801) {
            const float v = EXP2(xb[idx] * L2E);
            const unsigned byte = PK8(v);
            const unsigned r = ((unsigned)idx * 111111u) >> 24;   // idx / 151
            const int c = idx - 151 * (int)r;
            const int t = (int)r + c;
            const int w = 149 - (int)r + c;
            if (w >= 0) {                      // only cell (150,0) fails
                const int j  = w >> 1;         // slot, 0..149
                const int l3 = (j * 0x5556) >> 16;   // j / 3
                const int kk = j - 3 * l3;
                ((char*)ldsW)[t * 256 + 4 * l3 + kk] = (char)byte;
            }
        }
    }
    __syncthreads();
    if (tid >= 64) return;                     // waves 1-3 done

    // ---- phase B: DP on wave 0 ----
    const int lane = tid;
    const int j3 = 3 * lane;
    const bool isL50 = (lane == 50);
    const unsigned* rowp = ldsW;

    float Ha[3][3], Hb[3][3];
    #pragma unroll
    for (int k = 0; k < 3; ++k)
        #pragma unroll
        for (int c = 0; c < 3; ++c) { Ha[k][c] = 0.0f; Hb[k][c] = 0.0f; }

    // prime: V0..V3 = exp diags 0..3 (f32), R0..R3 = fp8 dwords diags 4..7
    float V0[3], V1[3], V2[3], V3[3];
    unsigned R0, R1, R2, R3;
    {
        const unsigned w0 = rowp[0 * 64 + lane], w1 = rowp[1 * 64 + lane];
        const unsigned w2 = rowp[2 * 64 + lane], w3 = rowp[3 * 64 + lane];
        V0[0]=CVT8(w0,0); V0[1]=CVT8(w0,1); V0[2]=CVT8(w0,2);
        V1[0]=CVT8(w1,0); V1[1]=CVT8(w1,1); V1[2]=CVT8(w1,2);
        V2[0]=CVT8(w2,0); V2[1]=CVT8(w2,1); V2[2]=CVT8(w2,2);
        V3[0]=CVT8(w3,0); V3[1]=CVT8(w3,1); V3[2]=CVT8(w3,2);
        R0 = rowp[4 * 64 + lane]; R1 = rowp[5 * 64 + lane];
        R2 = rowp[6 * 64 + lane]; R3 = rowp[7 * 64 + lane];
    }

    float oneE = 1.0f;   // 2^-E
    float E = 0.0f;      // wave-uniform block-scale exponent
    float S[3] = {0.0f, 0.0f, 0.0f};   // per-k score sums, scaled by 2^-E

    for (int d = 0; d < 296; d += 8) {
        stepQ<0>(d + 0, j3, lane, rowp, Hb, Ha, V0, V2, R0, oneE, S, isL50);
        stepQ<1>(d + 1, j3, lane, rowp, Ha, Hb, V1, V3, R1, oneE, S, isL50);
        stepQ<0>(d + 2, j3, lane, rowp, Hb, Ha, V2, V0, R2, oneE, S, isL50);
        stepQ<1>(d + 3, j3, lane, rowp, Ha, Hb, V3, V1, R3, oneE, S, isL50);
        stepQ<0>(d + 4, j3, lane, rowp, Hb, Ha, V0, V2, R0, oneE, S, isL50);
        stepQ<1>(d + 5, j3, lane, rowp, Ha, Hb, V1, V3, R1, oneE, S, isL50);
        stepQ<0>(d + 6, j3, lane, rowp, Hb, Ha, V2, V0, R2, oneE, S, isL50);
        // renorm decision from h(d+6) (newest = Ha); applied after step d+7.
        // Safety: RTHR=2^36, worst 8-step growth 2^78.4, 1-step apply lag
        // 2^9.8 -> max at apply < 2^125 (finite); RSC=2^-80; E tracks exactly.
        float m = Ha[0][0];
        m = fmaxf(m, Ha[0][1]); m = fmaxf(m, Ha[0][2]);
        m = fmaxf(m, Ha[1][0]); m = fmaxf(m, Ha[1][1]); m = fmaxf(m, Ha[1][2]);
        m = fmaxf(m, Ha[2][0]); m = fmaxf(m, Ha[2][1]); m = fmaxf(m, Ha[2][2]);
        const bool rn = __any(m > RTHR);
        const float sc = rn ? RSC : 1.0f;
        stepQ<1>(d + 7, j3, lane, rowp, Ha, Hb, V3, V1, R3, oneE, S, isL50);
        #pragma unroll
        for (int k = 0; k < 3; ++k)
            #pragma unroll
            for (int c = 0; c < 3; ++c) { Ha[k][c] *= sc; Hb[k][c] *= sc; }
        S[0] *= sc; S[1] *= sc; S[2] *= sc;
        oneE *= sc; E += rn ? EADD : 0.0f;
    }
    // tail: diags 296..298 (FIFO phase: 296 % 4 == 0)
    stepQ<0>(296, j3, lane, rowp, Hb, Ha, V0, V2, R0, oneE, S, isL50);
    stepQ<1>(297, j3, lane, rowp, Ha, Hb, V1, V3, R1, oneE, S, isL50);
    stepQ<0>(298, j3, lane, rowp, Hb, Ha, V2, V0, R2, oneE, S, isL50);

    // wave sum of S (E uniform across lanes)
    float St = (S[0] + S[1]) + S[2];
    #pragma unroll
    for (int off = 32; off; off >>= 1) St += __shfl_xor(St, off, 64);
    if (lane == 0) {
        const float val = LN2 * (E + LOG2(St));
        if (use_atomic) atomicAdd(out_atomic, val);
        else            part[b] = val;
    }
}

__global__ __launch_bounds__(256)
void final_reduce(const float* __restrict__ part, float* __restrict__ out) {
    const int t = threadIdx.x;
    float v = part[t] + part[t + 256];
    #pragma unroll
    for (int off = 32; off; off >>= 1) v += __shfl_xor(v, off);
    __shared__ float ws[4];
    if ((t & 63) == 0) ws[t >> 6] = v;
    __syncthreads();
    if (t == 0) out[0] = ws[0] + ws[1] + ws[2] + ws[3];
}

extern "C" void kernel_launch(void* const* d_in, const int* in_sizes, int n_in,
                              void* d_out, int out_size, void* d_ws, size_t ws_size,
                              hipStream_t stream) {
    const float* x = (const float*)d_in[0];
    float* out = (float*)d_out;

    if (ws_size >= 512 * sizeof(float)) {
        float* part = (float*)d_ws;
        sw_fp8<<<512, 256, 0, stream>>>(x, part, nullptr, 0);
        final_reduce<<<1, 256, 0, stream>>>(part, out);
    } else {
        hipMemsetAsync(out, 0, sizeof(float), stream);
        sw_fp8<<<512, 256, 0, stream>>>(x, nullptr, out, 1);
    }
}

// Round 15
// 49.769 us; speedup vs baseline: 1.5603x; 1.5603x over previous
//
#include <hip/hip_runtime.h>

// Smith-Waterman soft-DP, B=512, x: (512,151,151) f32, scalar output.
// 512 blocks x 256 threads; waves 1-3 only stage LDS then exit; wave 0 runs
// the DP. Linear-domain DP (H = exp(h) * 2^-E).
// Phase A: coalesced read of x[b], exp2 -> e5m2 byte (upper byte of f16,
// RNE) scattered into diag-major LDS [t][4*lane+k] (308x256B).
// Phase B: per step ONE ds_read_b32 (imm-offset, no clamps, no addr VALU),
// decode via cvt_f32_f16(byte<<8); Hsum-reuse (align-sum = stored h-sum of
// step d-2); per-lane range masks (cv = d-in-[Dlo,298-Dlo]); 4-step register
// FIFO; 2-3 bound-ctrl DPPs; per-k S accumulators; renorm every 8 steps.

#define CGO 6.737946999085467e-03f   // e^-5
#define CGE 3.678794411714423e-01f   // e^-1
#define L2E 1.4426950408889634f
#define LN2 0.6931471805599453f
#define RTHR 0x1p36f
#define RSC  0x1p-80f
#define EADD 80.0f

#if __has_builtin(__builtin_amdgcn_exp2f)
#define EXP2(x) __builtin_amdgcn_exp2f(x)
#else
static __device__ __forceinline__ float EXP2_(float x){float r;asm("v_exp_f32 %0, %1":"=v"(r):"v"(x));return r;}
#define EXP2(x) EXP2_(x)
#endif

#if __has_builtin(__builtin_amdgcn_logf)
#define LOG2(x) __builtin_amdgcn_logf(x)
#else
static __device__ __forceinline__ float LOG2_(float x){float r;asm("v_log_f32 %0, %1":"=v"(r):"v"(x));return r;}
#define LOG2(x) LOG2_(x)
#endif

#define DPP_UP 0x138   // wave_shr:1  (lane i <- i-1; lane 0 -> bound 0)
#define DPP_DN 0x130   // wave_shl:1  (lane i <- i+1; lane 63 -> bound 0)

template<int CTRL>
static __device__ __forceinline__ float dppz(float v){   // invalid lanes -> 0
    return __int_as_float(__builtin_amdgcn_update_dpp(
        0, __float_as_int(v), CTRL, 0xF, 0xF, true));
}

// decode: low 16 bits interpreted as f16 -> f32 (handles 0 / subnormals)
static __device__ __forceinline__ float dec16(unsigned bits16){
    unsigned short us = (unsigned short)bits16;
    _Float16 h;
    __builtin_memcpy(&h, &us, 2);
    return (float)h;
}

// ---- one anti-diagonal step (SO = d&1, compile-time) ----
// Slot j = 3*lane + k. Entry: Vs[k] = decoded value diag d, Vx[k] = diag
// d+2, Rc = e5m2x4 dword of diag d+4 (loaded 4 steps ago), HS[k] = h-sum of
// step d-2 (same parity). Computes h(d), accumulates S, stores new h-sum,
// commits Vs <- decode(Rc), loads Rc <- row(d+8) at ldsB+vaddr+IMM.
template<int SO>
static __device__ __forceinline__
void stepR(const int d, const char* ldsB, const int vaddr, const int IMM,
           const int (&Dlo)[3], const int (&Drg)[3],
           float (&H)[3][3], float (&HS)[3],
           float (&Vs)[3], float (&Vx)[3], unsigned& Rc,
           const float oneE, float (&S)[3], const bool isL50)
{
    // capture neighbor components (before H overwrite)
    float R0[3], R1[3], D0[3], D1[3], D2[3];
    if (SO) {   // odd: right <- h1[j-1]; down <- own h1
        R0[0] = dppz<DPP_UP>(H[2][0]);      // j-1 = 3(lane-1)+2
        R1[0] = dppz<DPP_UP>(H[2][1]);
        R0[1] = H[0][0]; R1[1] = H[0][1];
        R0[2] = H[1][0]; R1[2] = H[1][1];
        #pragma unroll
        for (int k = 0; k < 3; ++k) { D0[k]=H[k][0]; D1[k]=H[k][1]; D2[k]=H[k][2]; }
    } else {    // even: right <- own h1; down <- h1[j+1]
        #pragma unroll
        for (int k = 0; k < 3; ++k) { R0[k]=H[k][0]; R1[k]=H[k][1]; }
        D0[0]=H[1][0]; D1[0]=H[1][1]; D2[0]=H[1][2];
        D0[1]=H[2][0]; D1[1]=H[2][1]; D2[1]=H[2][2];
        D0[2]=dppz<DPP_DN>(H[0][0]);        // j+1 = 3(lane+1)+0
        D1[2]=dppz<DPP_DN>(H[0][1]);
        D2[2]=dppz<DPP_DN>(H[0][2]);
    }

    #pragma unroll
    for (int k = 0; k < 3; ++k) {
        // core-valid: d in [Dlo, 298-Dlo] (per-lane constants; pad slots
        // j>=150 may evaluate true but their Vs/Vx are 0 -> harmless)
        const bool cv = (unsigned)(d - Dlo[k]) <= (unsigned)Drg[k];
        const float sxl = cv ? Vs[k] : 0.0f;
        const float x2l = cv ? Vx[k] : 0.0f;

        const float h0 = sxl * (HS[k] + oneE);   // align: reuse stored h-sum(d-2)
        float h1 = fmaf(CGO, R0[k], CGE * R1[k]);
        const float h2 = fmaf(CGO, D0[k] + D1[k], CGE * D2[k]);
        if (SO && k == 0) h1 = isL50 ? 0.0f : h1;   // slot-150 sentinel (odd only)
        const float hs = (h0 + h1) + h2;
        S[k] = fmaf(x2l, hs, S[k]);
        H[k][0] = h0; H[k][1] = h1; H[k][2] = h2;
        HS[k] = hs;
    }

    // commit: Vs <- decode(Rc)  [Rc = diag d+4, loaded 4 steps ago]
    Vs[0] = dec16(Rc << 8);
    Vs[1] = dec16(Rc & 0xFF00u);
    Vs[2] = dec16((Rc >> 8) & 0xFF00u);
    // load diag d+8 directly into Rc (one dword, always in-bounds)
    Rc = *(const unsigned*)(ldsB + vaddr + IMM);
}

__global__ __launch_bounds__(256)
void sw_e5(const float* __restrict__ x, float* __restrict__ part,
           float* __restrict__ out_atomic, int use_atomic) {
    const int b = blockIdx.x;
    const float* xb = x + (size_t)b * 22801;
    const int tid = threadIdx.x;

    __shared__ char ldsB[79104];   // 308 rows x 256B diag-major e5m2 + dump row

    // ---- phase A0: zero-init (all 4 waves) ----
    {
        int4* l4 = (int4*)ldsB;
        for (int i = tid; i < 79104 / 16; i += 256) l4[i] = int4{0,0,0,0};
    }
    __syncthreads();

    // ---- phase A1: coalesced load + exp -> e5m2 byte scatter (all 4 waves) ----
    for (int i = 0; i < 90; ++i) {
        const int idx = i * 256 + tid;
        const int idc = idx > 22800 ? 22800 : idx;
        const float v = EXP2(xb[idc] * L2E);
        const _Float16 hv = (_Float16)v;          // RNE f32->f16
        unsigned short u16; __builtin_memcpy(&u16, &hv, 2);
        const unsigned byte = ((unsigned)u16 + 0x7Fu + ((u16 >> 8) & 1u)) >> 8; // RNE to e5m2
        const unsigned r = ((unsigned)idc * 111111u) >> 24;   // idc / 151
        const int c = idc - 151 * (int)r;
        const int t = (int)r + c;
        const int w = 149 - (int)r + c;
        const int j = w >> 1;
        const int l3 = (j * 0x5556) >> 16;        // j / 3
        const int kk = j - 3 * l3;
        int addr = t * 256 + 4 * l3 + kk;
        const bool ok = (idx <= 22800) & (w >= 0);  // excludes only cell (150,0)
        addr = ok ? addr : 78848;                   // dump row
        ldsB[addr] = (char)byte;
    }
    __syncthreads();
    if (tid >= 64) return;                          // waves 1-3 done

    // ---- phase B: DP on wave 0 ----
    const int lane = tid;
    const bool isL50 = (lane == 50);

    // per-lane mask constants: Dlo(j) = j<=74 ? 148-2j : 2j-149, Drg = 298-2*Dlo
    int Dlo[3], Drg[3];
    #pragma unroll
    for (int k = 0; k < 3; ++k) {
        const int j = 3 * lane + k;
        Dlo[k] = (j <= 74) ? (148 - 2 * j) : (2 * j - 149);
        Drg[k] = 298 - 2 * Dlo[k];
    }

    float H[3][3], HSe[3], HSo[3];
    #pragma unroll
    for (int k = 0; k < 3; ++k) {
        H[k][0] = 0.0f; H[k][1] = 0.0f; H[k][2] = 0.0f;
        HSe[k] = 0.0f; HSo[k] = 0.0f;
    }

    // prime: V0..V3 = decoded diags 0..3, R0..R3 = dwords diags 4..7
    float V0[3], V1[3], V2[3], V3[3];
    unsigned R0, R1, R2, R3;
    {
        const unsigned* rowp = (const unsigned*)ldsB;
        const unsigned w0 = rowp[0 * 64 + lane], w1 = rowp[1 * 64 + lane];
        const unsigned w2 = rowp[2 * 64 + lane], w3 = rowp[3 * 64 + lane];
        V0[0]=dec16(w0<<8); V0[1]=dec16(w0&0xFF00u); V0[2]=dec16((w0>>8)&0xFF00u);
        V1[0]=dec16(w1<<8); V1[1]=dec16(w1&0xFF00u); V1[2]=dec16((w1>>8)&0xFF00u);
        V2[0]=dec16(w2<<8); V2[1]=dec16(w2&0xFF00u); V2[2]=dec16((w2>>8)&0xFF00u);
        V3[0]=dec16(w3<<8); V3[1]=dec16(w3&0xFF00u); V3[2]=dec16((w3>>8)&0xFF00u);
        R0 = rowp[4 * 64 + lane]; R1 = rowp[5 * 64 + lane];
        R2 = rowp[6 * 64 + lane]; R3 = rowp[7 * 64 + lane];
    }

    int vaddr = 2048 + 4 * lane;   // byte addr of row 8, this lane
    float oneE = 1.0f;             // 2^-E
    float E = 0.0f;                // wave-uniform block-scale exponent
    float S[3] = {0.0f, 0.0f, 0.0f};

    for (int d = 0; d < 296; d += 8) {
        stepR<0>(d+0, ldsB, vaddr,    0, Dlo, Drg, H, HSe, V0, V2, R0, oneE, S, isL50);
        stepR<1>(d+1, ldsB, vaddr,  256, Dlo, Drg, H, HSo, V1, V3, R1, oneE, S, isL50);
        stepR<0>(d+2, ldsB, vaddr,  512, Dlo, Drg, H, HSe, V2, V0, R2, oneE, S, isL50);
        stepR<1>(d+3, ldsB, vaddr,  768, Dlo, Drg, H, HSo, V3, V1, R3, oneE, S, isL50);
        stepR<0>(d+4, ldsB, vaddr, 1024, Dlo, Drg, H, HSe, V0, V2, R0, oneE, S, isL50);
        stepR<1>(d+5, ldsB, vaddr, 1280, Dlo, Drg, H, HSo, V1, V3, R1, oneE, S, isL50);
        stepR<0>(d+6, ldsB, vaddr, 1536, Dlo, Drg, H, HSe, V2, V0, R2, oneE, S, isL50);
        // renorm decision from h(d+6) (= H now); applied after step d+7.
        // Safety: RTHR=2^36, worst 8-step growth 2^78, 1-step lag 2^9.7,
        // h-sum factor 3 -> max at apply < 2^126 (finite); RSC=2^-80.
        float m = H[0][0];
        m = fmaxf(m, H[0][1]); m = fmaxf(m, H[0][2]);
        m = fmaxf(m, H[1][0]); m = fmaxf(m, H[1][1]); m = fmaxf(m, H[1][2]);
        m = fmaxf(m, H[2][0]); m = fmaxf(m, H[2][1]); m = fmaxf(m, H[2][2]);
        const bool rn = __any(m > RTHR);
        const float sc = rn ? RSC : 1.0f;
        stepR<1>(d+7, ldsB, vaddr, 1792, Dlo, Drg, H, HSo, V3, V1, R3, oneE, S, isL50);
        #pragma unroll
        for (int k = 0; k < 3; ++k) {
            H[k][0] *= sc; H[k][1] *= sc; H[k][2] *= sc;
            HSe[k] *= sc; HSo[k] *= sc; S[k] *= sc;
        }
        oneE *= sc; E += rn ? EADD : 0.0f;
        vaddr += 2048;
    }
    // tail: diags 296..298 (FIFO phase: 296 % 8 == 0)
    stepR<0>(296, ldsB, vaddr,   0, Dlo, Drg, H, HSe, V0, V2, R0, oneE, S, isL50);
    stepR<1>(297, ldsB, vaddr, 256, Dlo, Drg, H, HSo, V1, V3, R1, oneE, S, isL50);
    stepR<0>(298, ldsB, vaddr, 512, Dlo, Drg, H, HSe, V2, V0, R2, oneE, S, isL50);

    // wave sum of S (E uniform across lanes)
    float St = (S[0] + S[1]) + S[2];
    #pragma unroll
    for (int off = 32; off; off >>= 1) St += __shfl_xor(St, off, 64);
    if (lane == 0) {
        const float val = LN2 * (E + LOG2(St));
        if (use_atomic) atomicAdd(out_atomic, val);
        else            part[b] = val;
    }
}

__global__ __launch_bounds__(256)
void final_reduce(const float* __restrict__ part, float* __restrict__ out) {
    const int t = threadIdx.x;
    float v = part[t] + part[t + 256];
    #pragma unroll
    for (int off = 32; off; off >>= 1) v += __shfl_xor(v, off);
    __shared__ float ws[4];
    if ((t & 63) == 0) ws[t >> 6] = v;
    __syncthreads();
    if (t == 0) out[0] = ws[0] + ws[1] + ws[2] + ws[3];
}

extern "C" void kernel_launch(void* const* d_in, const int* in_sizes, int n_in,
                              void* d_out, int out_size, void* d_ws, size_t ws_size,
                              hipStream_t stream) {
    const float* x = (const float*)d_in[0];
    float* out = (float*)d_out;

    if (ws_size >= 512 * sizeof(float)) {
        float* part = (float*)d_ws;
        sw_e5<<<512, 256, 0, stream>>>(x, part, nullptr, 0);
        final_reduce<<<1, 256, 0, stream>>>(part, out);
    } else {
        hipMemsetAsync(out, 0, sizeof(float), stream);
        sw_e5<<<512, 256, 0, stream>>>(x, nullptr, out, 1);
    }
}

// Round 16
// 49.720 us; speedup vs baseline: 1.5618x; 1.0010x over previous
//
#include <hip/hip_runtime.h>

// Smith-Waterman soft-DP, B=512, x: (512,151,151) f32, scalar output.
// 512 blocks x 256 threads; waves 1-3 stage LDS then exit; wave 0 runs DP.
// Linear-domain DP (H = exp(h) * 2^-E).
// Phase A: coalesced read of x[b], exp2 -> e5m2 byte (upper byte of f16,
// RNE) scattered into diag-major LDS [t][4*lane+k] (308x256B).
// Phase B: ping-pong H banks (HA/HB, zero capture copies); ONE ds_read_b32
// per step (imm-offset); decode via cvt_f32_f16(byte<<8); Hsum reuse;
// per-lane range masks; 4-step register FIFO; 2-3 bound-ctrl DPPs;
// per-k S accumulators; renorm every 8 steps with early decision.

#define CGO 6.737946999085467e-03f   // e^-5
#define CGE 3.678794411714423e-01f   // e^-1
#define L2E 1.4426950408889634f
#define LN2 0.6931471805599453f
#define RTHR 0x1p36f
#define RSC  0x1p-80f
#define EADD 80.0f

#if __has_builtin(__builtin_amdgcn_exp2f)
#define EXP2(x) __builtin_amdgcn_exp2f(x)
#else
static __device__ __forceinline__ float EXP2_(float x){float r;asm("v_exp_f32 %0, %1":"=v"(r):"v"(x));return r;}
#define EXP2(x) EXP2_(x)
#endif

#if __has_builtin(__builtin_amdgcn_logf)
#define LOG2(x) __builtin_amdgcn_logf(x)
#else
static __device__ __forceinline__ float LOG2_(float x){float r;asm("v_log_f32 %0, %1":"=v"(r):"v"(x));return r;}
#define LOG2(x) LOG2_(x)
#endif

#define DPP_UP 0x138   // wave_shr:1  (lane i <- i-1; lane 0 -> bound 0)
#define DPP_DN 0x130   // wave_shl:1  (lane i <- i+1; lane 63 -> bound 0)

template<int CTRL>
static __device__ __forceinline__ float dppz(float v){   // invalid lanes -> 0
    return __int_as_float(__builtin_amdgcn_update_dpp(
        0, __float_as_int(v), CTRL, 0xF, 0xF, true));
}

// decode: low 16 bits interpreted as f16 -> f32 (handles 0 / subnormals)
static __device__ __forceinline__ float dec16(unsigned bits16){
    unsigned short us = (unsigned short)bits16;
    _Float16 h;
    __builtin_memcpy(&h, &us, 2);
    return (float)h;
}

// ---- one anti-diagonal step (SO = d&1, compile-time) ----
// Slot j = 3*lane + k. Hr = h(d-1) [read bank], Hw = dead h(d-2) storage
// [write bank, receives h(d)]. Vs[k] = decoded diag d, Vx[k] = diag d+2,
// Rc = e5m2x4 dword of diag d+4 (loaded 4 steps ago), HS[k] = h-sum(d-2).
template<int SO>
static __device__ __forceinline__
void stepS(const int d, const char* ldsB, const int vaddr, const int IMM,
           const int (&Dlo)[3], const int (&Drg)[3],
           const float (&Hr)[3][3], float (&Hw)[3][3], float (&HS)[3],
           float (&Vs)[3], float (&Vx)[3], unsigned& Rc,
           const float oneE, float (&S)[3], const bool isL50)
{
    // k=0 / k=2 cross-lane neighbor comps (direct from read bank)
    float u0, u1, w0, w1, w2;
    if (SO) {   // odd: right(j-1) for k=0 <- lane-1's k=2
        u0 = dppz<DPP_UP>(Hr[2][0]);
        u1 = dppz<DPP_UP>(Hr[2][1]);
        w0 = w1 = w2 = 0.0f;
    } else {    // even: down(j+1) for k=2 <- lane+1's k=0
        w0 = dppz<DPP_DN>(Hr[0][0]);
        w1 = dppz<DPP_DN>(Hr[0][1]);
        w2 = dppz<DPP_DN>(Hr[0][2]);
        u0 = u1 = 0.0f;
    }

    #pragma unroll
    for (int k = 0; k < 3; ++k) {
        // right comps (R0,R1) and down comps (D0,D1,D2), read directly
        float R0, R1, D0, D1, D2;
        if (SO) {   // right <- h1[j-1]; down <- own h1
            if (k == 0) { R0 = u0; R1 = u1; }
            else        { R0 = Hr[k-1][0]; R1 = Hr[k-1][1]; }
            D0 = Hr[k][0]; D1 = Hr[k][1]; D2 = Hr[k][2];
        } else {    // right <- own h1; down <- h1[j+1]
            R0 = Hr[k][0]; R1 = Hr[k][1];
            if (k == 2) { D0 = w0; D1 = w1; D2 = w2; }
            else        { D0 = Hr[k+1][0]; D1 = Hr[k+1][1]; D2 = Hr[k+1][2]; }
        }

        // core-valid: d in [Dlo, 298-Dlo] (per-lane constants)
        const bool cv = (unsigned)(d - Dlo[k]) <= (unsigned)Drg[k];
        const float sxl = cv ? Vs[k] : 0.0f;
        const float x2l = cv ? Vx[k] : 0.0f;

        const float h0 = sxl * (HS[k] + oneE);   // align: h-sum(d-2) reuse
        float h1 = fmaf(CGO, R0, CGE * R1);
        const float h2 = fmaf(CGO, D0 + D1, CGE * D2);
        if (SO && k == 0) h1 = isL50 ? 0.0f : h1;   // slot-150 sentinel
        const float hs = (h0 + h1) + h2;
        S[k] = fmaf(x2l, hs, S[k]);
        Hw[k][0] = h0; Hw[k][1] = h1; Hw[k][2] = h2;
        HS[k] = hs;
    }

    // commit: Vs <- decode(Rc)  [Rc = diag d+4, loaded 4 steps ago]
    Vs[0] = dec16(Rc << 8);
    Vs[1] = dec16(Rc & 0xFF00u);
    Vs[2] = dec16((Rc >> 8) & 0xFF00u);
    // load diag d+8 directly into Rc (one dword, always in-bounds)
    Rc = *(const unsigned*)(ldsB + vaddr + IMM);
}

__global__ __launch_bounds__(256)
void sw_bank(const float* __restrict__ x, float* __restrict__ part,
             float* __restrict__ out_atomic, int use_atomic) {
    const int b = blockIdx.x;
    const float* xb = x + (size_t)b * 22801;
    const int tid = threadIdx.x;

    __shared__ char ldsB[79104];   // 308 rows x 256B diag-major e5m2 + dump row

    // ---- phase A0: zero-init (all 4 waves) ----
    {
        int4* l4 = (int4*)ldsB;
        for (int i = tid; i < 79104 / 16; i += 256) l4[i] = int4{0,0,0,0};
    }
    __syncthreads();

    // ---- phase A1: coalesced load + exp -> e5m2 byte scatter (all 4 waves) ----
    for (int i = 0; i < 90; ++i) {
        const int idx = i * 256 + tid;
        const int idc = idx > 22800 ? 22800 : idx;
        const float v = EXP2(xb[idc] * L2E);
        const _Float16 hv = (_Float16)v;          // RNE f32->f16
        unsigned short u16; __builtin_memcpy(&u16, &hv, 2);
        const unsigned byte = ((unsigned)u16 + 0x7Fu + ((u16 >> 8) & 1u)) >> 8; // RNE to e5m2
        const unsigned r = ((unsigned)idc * 111111u) >> 24;   // idc / 151
        const int c = idc - 151 * (int)r;
        const int t = (int)r + c;
        const int w = 149 - (int)r + c;
        const int j = w >> 1;
        const int l3 = (j * 0x5556) >> 16;        // j / 3
        const int kk = j - 3 * l3;
        int addr = t * 256 + 4 * l3 + kk;
        const bool ok = (idx <= 22800) & (w >= 0);  // excludes only cell (150,0)
        addr = ok ? addr : 78848;                   // dump row
        ldsB[addr] = (char)byte;
    }
    __syncthreads();
    if (tid >= 64) return;                          // waves 1-3 done

    // ---- phase B: DP on wave 0 ----
    const int lane = tid;
    const bool isL50 = (lane == 50);

    // per-lane mask constants: Dlo(j) = j<=74 ? 148-2j : 2j-149, Drg = 298-2*Dlo
    int Dlo[3], Drg[3];
    #pragma unroll
    for (int k = 0; k < 3; ++k) {
        const int j = 3 * lane + k;
        Dlo[k] = (j <= 74) ? (148 - 2 * j) : (2 * j - 149);
        Drg[k] = 298 - 2 * Dlo[k];
    }

    float HA[3][3], HB[3][3], HSe[3], HSo[3];
    #pragma unroll
    for (int k = 0; k < 3; ++k) {
        HA[k][0] = 0.0f; HA[k][1] = 0.0f; HA[k][2] = 0.0f;
        HB[k][0] = 0.0f; HB[k][1] = 0.0f; HB[k][2] = 0.0f;
        HSe[k] = 0.0f; HSo[k] = 0.0f;
    }

    // prime: V0..V3 = decoded diags 0..3, R0..R3 = dwords diags 4..7
    float V0[3], V1[3], V2[3], V3[3];
    unsigned R0, R1, R2, R3;
    {
        const unsigned* rowp = (const unsigned*)ldsB;
        const unsigned w0 = rowp[0 * 64 + lane], w1 = rowp[1 * 64 + lane];
        const unsigned w2 = rowp[2 * 64 + lane], w3 = rowp[3 * 64 + lane];
        V0[0]=dec16(w0<<8); V0[1]=dec16(w0&0xFF00u); V0[2]=dec16((w0>>8)&0xFF00u);
        V1[0]=dec16(w1<<8); V1[1]=dec16(w1&0xFF00u); V1[2]=dec16((w1>>8)&0xFF00u);
        V2[0]=dec16(w2<<8); V2[1]=dec16(w2&0xFF00u); V2[2]=dec16((w2>>8)&0xFF00u);
        V3[0]=dec16(w3<<8); V3[1]=dec16(w3&0xFF00u); V3[2]=dec16((w3>>8)&0xFF00u);
        R0 = rowp[4 * 64 + lane]; R1 = rowp[5 * 64 + lane];
        R2 = rowp[6 * 64 + lane]; R3 = rowp[7 * 64 + lane];
    }

    int vaddr = 2048 + 4 * lane;   // byte addr of row 8, this lane
    float oneE = 1.0f;             // 2^-E
    float E = 0.0f;                // wave-uniform block-scale exponent
    float S[3] = {0.0f, 0.0f, 0.0f};

    // even step d: reads HB (h(d-1)), writes HA (h(d)); odd: reads HA, writes HB
    for (int d = 0; d < 296; d += 8) {
        stepS<0>(d+0, ldsB, vaddr,    0, Dlo, Drg, HB, HA, HSe, V0, V2, R0, oneE, S, isL50);
        stepS<1>(d+1, ldsB, vaddr,  256, Dlo, Drg, HA, HB, HSo, V1, V3, R1, oneE, S, isL50);
        stepS<0>(d+2, ldsB, vaddr,  512, Dlo, Drg, HB, HA, HSe, V2, V0, R2, oneE, S, isL50);
        stepS<1>(d+3, ldsB, vaddr,  768, Dlo, Drg, HA, HB, HSo, V3, V1, R3, oneE, S, isL50);
        stepS<0>(d+4, ldsB, vaddr, 1024, Dlo, Drg, HB, HA, HSe, V0, V2, R0, oneE, S, isL50);
        stepS<1>(d+5, ldsB, vaddr, 1280, Dlo, Drg, HA, HB, HSo, V1, V3, R1, oneE, S, isL50);
        stepS<0>(d+6, ldsB, vaddr, 1536, Dlo, Drg, HB, HA, HSe, V2, V0, R2, oneE, S, isL50);
        // renorm decision from h(d+6) (= HA); applied after step d+7.
        // Safety: RTHR=2^36, worst 8-step growth 2^78, 1-step lag 2^9.7,
        // h-sum factor 3 -> max at apply < 2^126 (finite); RSC=2^-80.
        float m = HA[0][0];
        m = fmaxf(m, HA[0][1]); m = fmaxf(m, HA[0][2]);
        m = fmaxf(m, HA[1][0]); m = fmaxf(m, HA[1][1]); m = fmaxf(m, HA[1][2]);
        m = fmaxf(m, HA[2][0]); m = fmaxf(m, HA[2][1]); m = fmaxf(m, HA[2][2]);
        const bool rn = __any(m > RTHR);
        const float sc = rn ? RSC : 1.0f;
        stepS<1>(d+7, ldsB, vaddr, 1792, Dlo, Drg, HA, HB, HSo, V3, V1, R3, oneE, S, isL50);
        #pragma unroll
        for (int k = 0; k < 3; ++k) {
            HA[k][0] *= sc; HA[k][1] *= sc; HA[k][2] *= sc;
            HB[k][0] *= sc; HB[k][1] *= sc; HB[k][2] *= sc;
            HSe[k] *= sc; HSo[k] *= sc; S[k] *= sc;
        }
        oneE *= sc; E += rn ? EADD : 0.0f;
        vaddr += 2048;
    }
    // tail: diags 296..298 (FIFO phase: 296 % 8 == 0)
    stepS<0>(296, ldsB, vaddr,   0, Dlo, Drg, HB, HA, HSe, V0, V2, R0, oneE, S, isL50);
    stepS<1>(297, ldsB, vaddr, 256, Dlo, Drg, HA, HB, HSo, V1, V3, R1, oneE, S, isL50);
    stepS<0>(298, ldsB, vaddr, 512, Dlo, Drg, HB, HA, HSe, V2, V0, R2, oneE, S, isL50);

    // wave sum of S (E uniform across lanes)
    float St = (S[0] + S[1]) + S[2];
    #pragma unroll
    for (int off = 32; off; off >>= 1) St += __shfl_xor(St, off, 64);
    if (lane == 0) {
        const float val = LN2 * (E + LOG2(St));
        if (use_atomic) atomicAdd(out_atomic, val);
        else            part[b] = val;
    }
}

__global__ __launch_bounds__(256)
void final_reduce(const float* __restrict__ part, float* __restrict__ out) {
    const int t = threadIdx.x;
    float v = part[t] + part[t + 256];
    #pragma unroll
    for (int off = 32; off; off >>= 1) v += __shfl_xor(v, off);
    __shared__ float ws[4];
    if ((t & 63) == 0) ws[t >> 6] = v;
    __syncthreads();
    if (t == 0) out[0] = ws[0] + ws[1] + ws[2] + ws[3];
}

extern "C" void kernel_launch(void* const* d_in, const int* in_sizes, int n_in,
                              void* d_out, int out_size, void* d_ws, size_t ws_size,
                              hipStream_t stream) {
    const float* x = (const float*)d_in[0];
    float* out = (float*)d_out;

    if (ws_size >= 512 * sizeof(float)) {
        float* part = (float*)d_ws;
        sw_bank<<<512, 256, 0, stream>>>(x, part, nullptr, 0);
        final_reduce<<<1, 256, 0, stream>>>(part, out);
    } else {
        hipMemsetAsync(out, 0, sizeof(float), stream);
        sw_bank<<<512, 256, 0, stream>>>(x, nullptr, out, 1);
    }
}

// Round 17
// 35.870 us; speedup vs baseline: 2.1648x; 1.3861x over previous
//
#include <hip/hip_runtime.h>

// Smith-Waterman soft-DP, B=512, x: (512,151,151) f32, scalar output.
// ROW-SCAN formulation: 150 row iterations (vs 299 anti-diagonals).
// h1's along-row linear recurrence (h1(c) = e^-5*h0(c-1) + e^-1*h1(c-1))
// is solved per row by a weighted parallel prefix scan in registers
// (DPP row_shr 1/2/4/8 + row_bcast15/31). h0/h2/score are previous-row
// local FMAs. Lane packing c = 3*lane + k. Linear domain H = exp(h)*2^-E.
// x staged as e5m2 bytes, row-major [row][4*lane+k] (152x256B LDS).
// 512 blocks x 256 threads; waves 1-3 stage then exit; wave 0 runs DP.

#define CGO 6.737946999085467e-03f   // e^-5
#define CGE 3.678794411714423e-01f   // e^-1
#define L2E 1.4426950408889634f
#define LN2 0.6931471805599453f
#define RTHR 0x1p28f
#define RSC  0x1p-64f
#define EADD 64.0f

// scan constants: A = e^-3 (per-lane carry factor, 3 cells/lane)
#define SA1 4.9787068367863944e-02f   // e^-3
#define SA2 2.4787521766663585e-03f   // e^-6
#define SA4 6.1442123533282098e-06f   // e^-12
#define SA8 3.7751345442790977e-11f   // e^-24
#define CA1 3.6787944117144233e-01f   // e^-1
#define CA2 1.3533528323661270e-01f   // e^-2
#define CA3 4.9787068367863944e-02f   // e^-3

#if __has_builtin(__builtin_amdgcn_exp2f)
#define EXP2(x) __builtin_amdgcn_exp2f(x)
#else
static __device__ __forceinline__ float EXP2_(float x){float r;asm("v_exp_f32 %0, %1":"=v"(r):"v"(x));return r;}
#define EXP2(x) EXP2_(x)
#endif

#if __has_builtin(__builtin_amdgcn_logf)
#define LOG2(x) __builtin_amdgcn_logf(x)
#else
static __device__ __forceinline__ float LOG2_(float x){float r;asm("v_log_f32 %0, %1":"=v"(r):"v"(x));return r;}
#define LOG2(x) LOG2_(x)
#endif

#define DPP_UP   0x138   // wave_shr:1 (lane i <- i-1; lane 0 -> 0)
#define DPP_DN   0x130   // wave_shl:1 (lane i <- i+1; lane 63 -> 0)
#define ROW_SHR1 0x111
#define ROW_SHR2 0x112
#define ROW_SHR4 0x114
#define ROW_SHR8 0x118
#define BCAST15  0x142
#define BCAST31  0x143

template<int CTRL>
static __device__ __forceinline__ float dppz(float v){   // invalid lanes -> 0
    return __int_as_float(__builtin_amdgcn_update_dpp(
        0, __float_as_int(v), CTRL, 0xF, 0xF, true));
}

// decode: low 16 bits interpreted as f16 -> f32
static __device__ __forceinline__ float dec16(unsigned bits16){
    unsigned short us = (unsigned short)bits16;
    _Float16 h;
    __builtin_memcpy(&h, &us, 2);
    return (float)h;
}

// ---- one row step (row r). Entry: SX[k] = exp(x[r, 3l+k]); Rc = raw e5m2
// dword of row r+1; HSs[k] = hs(r-1, c-1) (shifted); g[k] = (h0+h1)(r-1,c);
// h2p[k] = h2(r-1,c). Issues load of row r+2; x2 comes from decoding Rc.
template<int IMM>
static __device__ __forceinline__
void stepRow(const char* ldsB, const int vaddr,
             const float vA16, const float vA32,
             float (&SX)[3], unsigned& Rc,
             float (&HSs)[3], float (&g)[3], float (&h2p)[3],
             const float oneE, float (&S)[3])
{
    const unsigned Rn = *(const unsigned*)(ldsB + vaddr + IMM);  // row r+2
    // decode row r+1 (x2 for this row; sx for next row)
    const float D0 = dec16(Rc << 8);
    const float D1 = dec16(Rc & 0xFF00u);
    const float D2 = dec16((Rc >> 8) & 0xFF00u);
    const float D3 = dppz<DPP_DN>(D0);          // byte0 of lane+1

    // h0(r,c) = sx * (hs(r-1,c-1) + oneE)
    const float h00 = SX[0] * (HSs[0] + oneE);
    const float h01 = SX[1] * (HSs[1] + oneE);
    const float h02 = SX[2] * (HSs[2] + oneE);

    // b(c) = CGO * h0(r, c-1)
    const float h0u = dppz<DPP_UP>(h02);
    const float b0 = CGO * h0u;
    const float b1 = CGO * h00;
    const float b2 = CGO * h01;

    // local prefix within lane (cells k=0,1,2)
    const float p1 = fmaf(CGE, b0, b1);
    const float p2 = fmaf(CGE, p1, b2);

    // cross-lane exclusive weighted scan of lane totals (factor A=e^-3):
    // C(lane) = sum_{j<lane} A^(lane-j) * p2(j)
    float t = dppz<DPP_UP>(p2);
    t = fmaf(SA1, dppz<ROW_SHR1>(t), t);
    t = fmaf(SA2, dppz<ROW_SHR2>(t), t);
    t = fmaf(SA4, dppz<ROW_SHR4>(t), t);
    t = fmaf(SA8, dppz<ROW_SHR8>(t), t);
    t = fmaf(vA16, dppz<BCAST15>(t), t);
    t = fmaf(vA32, dppz<BCAST31>(t), t);

    // h1_k = p_k + CGE^{k+1} * C
    const float h10 = fmaf(CA1, t, b0);
    const float h11 = fmaf(CA2, t, p1);
    const float h12 = fmaf(CA3, t, p2);

    // h2(r,c) = CGO*(h0+h1)(r-1,c) + CGE*h2(r-1,c)
    const float h20 = fmaf(CGO, g[0], CGE * h2p[0]);
    const float h21 = fmaf(CGO, g[1], CGE * h2p[1]);
    const float h22 = fmaf(CGO, g[2], CGE * h2p[2]);

    // g = h0+h1; hs = g+h2
    g[0] = h00 + h10; g[1] = h01 + h11; g[2] = h02 + h12;
    const float hs0 = g[0] + h20;
    const float hs1 = g[1] + h21;
    const float hs2 = g[2] + h22;
    h2p[0] = h20; h2p[1] = h21; h2p[2] = h22;

    // score: x2(r,c) = exp(x[r+1, c+1]) = (D1, D2, D3); zero-stored bytes
    // auto-gate non-core cells (no masks needed)
    S[0] = fmaf(D1, hs0, S[0]);
    S[1] = fmaf(D2, hs1, S[1]);
    S[2] = fmaf(D3, hs2, S[2]);

    // next-row prep
    HSs[0] = dppz<DPP_UP>(hs2);
    HSs[1] = hs0; HSs[2] = hs1;
    SX[0] = D0; SX[1] = D1; SX[2] = D2;
    Rc = Rn;
}

__global__ __launch_bounds__(256)
void sw_row(const float* __restrict__ x, float* __restrict__ part,
            float* __restrict__ out_atomic, int use_atomic) {
    const int b = blockIdx.x;
    const float* xb = x + (size_t)b * 22801;
    const int tid = threadIdx.x;

    __shared__ char ldsB[38912];   // 152 rows x 256B (row-major e5m2)

    // ---- phase A0: zero-init (all 4 waves) ----
    {
        int4* l4 = (int4*)ldsB;
        for (int i = tid; i < 38912 / 16; i += 256) l4[i] = int4{0,0,0,0};
    }
    __syncthreads();

    // ---- phase A1: coalesced load + exp -> e5m2 byte scatter ----
    for (int i = 0; i < 90; ++i) {
        const int idx = i * 256 + tid;
        const int idc = idx > 22800 ? 22800 : idx;
        const float v = EXP2(xb[idc] * L2E);
        const _Float16 hv = (_Float16)v;          // RNE f32->f16
        unsigned short u16; __builtin_memcpy(&u16, &hv, 2);
        const unsigned byte = ((unsigned)u16 + 0x7Fu + ((u16 >> 8) & 1u)) >> 8;
        const unsigned r = ((unsigned)idc * 111111u) >> 24;   // idc / 151
        const int c = idc - 151 * (int)r;
        const int l3 = (c * 0x5556) >> 16;        // c / 3
        const int kk = c - 3 * l3;
        ldsB[(int)r * 256 + 4 * l3 + kk] = (char)byte;
    }
    __syncthreads();
    if (tid >= 64) return;                        // waves 1-3 done

    // ---- phase B: DP on wave 0 ----
    const int lane = tid;
    // per-lane bcast weight vectors: A^{(lane&15)+1}, A^{(lane&31)+1}
    const float vA16 = EXP2(-4.3280851226668902f * (float)((lane & 15) + 1));
    const float vA32 = EXP2(-4.3280851226668902f * (float)((lane & 31) + 1));
    const int vl4 = 4 * lane;

    float SX[3];
    unsigned Rc;
    {
        const unsigned w0 = *(const unsigned*)(ldsB + vl4);         // row 0
        SX[0] = dec16(w0 << 8);
        SX[1] = dec16(w0 & 0xFF00u);
        SX[2] = dec16((w0 >> 8) & 0xFF00u);
        Rc = *(const unsigned*)(ldsB + 256 + vl4);                  // row 1
    }
    float HSs[3] = {0.0f, 0.0f, 0.0f};
    float g[3]   = {0.0f, 0.0f, 0.0f};
    float h2p[3] = {0.0f, 0.0f, 0.0f};
    float S[3]   = {0.0f, 0.0f, 0.0f};
    float oneE = 1.0f;   // 2^-E
    float E = 0.0f;

    int vaddr = 512 + vl4;   // byte addr of row 2

    for (int gi = 0; gi < 18; ++gi) {   // rows 8gi .. 8gi+7
        stepRow<   0>(ldsB, vaddr, vA16, vA32, SX, Rc, HSs, g, h2p, oneE, S);
        stepRow< 256>(ldsB, vaddr, vA16, vA32, SX, Rc, HSs, g, h2p, oneE, S);
        stepRow< 512>(ldsB, vaddr, vA16, vA32, SX, Rc, HSs, g, h2p, oneE, S);
        stepRow< 768>(ldsB, vaddr, vA16, vA32, SX, Rc, HSs, g, h2p, oneE, S);
        stepRow<1024>(ldsB, vaddr, vA16, vA32, SX, Rc, HSs, g, h2p, oneE, S);
        stepRow<1280>(ldsB, vaddr, vA16, vA32, SX, Rc, HSs, g, h2p, oneE, S);
        stepRow<1536>(ldsB, vaddr, vA16, vA32, SX, Rc, HSs, g, h2p, oneE, S);
        // renorm decision from row 8gi+6 state; applied after row 8gi+7.
        // Safety: RTHR=2^28, worst growth ~2^8.2/row -> <=2^102 at apply.
        float m = fmaxf(fmaxf(g[0], g[1]), g[2]);
        m = fmaxf(m, fmaxf(fmaxf(h2p[0], h2p[1]), h2p[2]));
        const bool rn = __any(m > RTHR);
        const float sc = rn ? RSC : 1.0f;
        stepRow<1792>(ldsB, vaddr, vA16, vA32, SX, Rc, HSs, g, h2p, oneE, S);
        #pragma unroll
        for (int k = 0; k < 3; ++k) {
            HSs[k] *= sc; g[k] *= sc; h2p[k] *= sc; S[k] *= sc;
        }
        oneE *= sc; E += rn ? EADD : 0.0f;
        vaddr += 2048;
    }
    // tail rows 144..149 (loads reach row 151 = zero pad)
    stepRow<   0>(ldsB, vaddr, vA16, vA32, SX, Rc, HSs, g, h2p, oneE, S);
    stepRow< 256>(ldsB, vaddr, vA16, vA32, SX, Rc, HSs, g, h2p, oneE, S);
    stepRow< 512>(ldsB, vaddr, vA16, vA32, SX, Rc, HSs, g, h2p, oneE, S);
    stepRow< 768>(ldsB, vaddr, vA16, vA32, SX, Rc, HSs, g, h2p, oneE, S);
    stepRow<1024>(ldsB, vaddr, vA16, vA32, SX, Rc, HSs, g, h2p, oneE, S);
    stepRow<1280>(ldsB, vaddr, vA16, vA32, SX, Rc, HSs, g, h2p, oneE, S);

    // wave sum of S (E uniform across lanes)
    float St = (S[0] + S[1]) + S[2];
    #pragma unroll
    for (int off = 32; off; off >>= 1) St += __shfl_xor(St, off, 64);
    if (lane == 0) {
        const float val = LN2 * (E + LOG2(St));
        if (use_atomic) atomicAdd(out_atomic, val);
        else            part[b] = val;
    }
}

__global__ __launch_bounds__(256)
void final_reduce(const float* __restrict__ part, float* __restrict__ out) {
    const int t = threadIdx.x;
    float v = part[t] + part[t + 256];
    #pragma unroll
    for (int off = 32; off; off >>= 1) v += __shfl_xor(v, off);
    __shared__ float ws[4];
    if ((t & 63) == 0) ws[t >> 6] = v;
    __syncthreads();
    if (t == 0) out[0] = ws[0] + ws[1] + ws[2] + ws[3];
}

extern "C" void kernel_launch(void* const* d_in, const int* in_sizes, int n_in,
                              void* d_out, int out_size, void* d_ws, size_t ws_size,
                              hipStream_t stream) {
    const float* x = (const float*)d_in[0];
    float* out = (float*)d_out;

    if (ws_size >= 512 * sizeof(float)) {
        float* part = (float*)d_ws;
        sw_row<<<512, 256, 0, stream>>>(x, part, nullptr, 0);
        final_reduce<<<1, 256, 0, stream>>>(part, out);
    } else {
        hipMemsetAsync(out, 0, sizeof(float), stream);
        sw_row<<<512, 256, 0, stream>>>(x, nullptr, out, 1);
    }
}